// Round 5
// baseline (47.767 us; speedup 1.0000x reference)
//
#include <hip/hip_runtime.h>
#include <hip/hip_bf16.h>
#include <math.h>

#define NB 2
#define SEQ 2048
#define DMODEL 512
#define NH 8
#define HDIM 64
#define NROWS (NB*SEQ)
#define HALF 256
#define NT 3   // key-tile lookback (min omitted delta = 129, gamma^129/(1-g)*|sv| ~ 6e-4)

typedef __attribute__((ext_vector_type(8))) short short8;
typedef __attribute__((ext_vector_type(4))) float f32x4;
typedef __attribute__((ext_vector_type(8))) unsigned short ushort8_t;

__device__ __forceinline__ unsigned short f2bf(float f) {
  union { float f; unsigned u; } v; v.f = f;
  unsigned r = v.u + 0x7fffu + ((v.u >> 16) & 1u);
  return (unsigned short)(r >> 16);
}
__device__ __forceinline__ float bf2f(unsigned short h) {
  union { unsigned u; float f; } v; v.u = ((unsigned)h) << 16;
  return v.f;
}

// async global->LDS, 16B per lane; LDS dest is wave-uniform base + lane*16
__device__ __forceinline__ void gload16(const void* g, void* l) {
  __builtin_amdgcn_global_load_lds(
      (const __attribute__((address_space(1))) unsigned int*)g,
      (__attribute__((address_space(3))) unsigned int*)l, 16, 0, 0);
}

// ---- fused prep: xpos tables | X->bf16 | W transpose+convert x3 ----
__global__ __launch_bounds__(256) void k_prep(
    const float* __restrict__ X, const float* __restrict__ Wq,
    const float* __restrict__ Wk, const float* __restrict__ Wv,
    float2* __restrict__ tab, unsigned short* __restrict__ Xb,
    unsigned short* __restrict__ Wtq, unsigned short* __restrict__ Wtk,
    unsigned short* __restrict__ Wtv) {
  __shared__ float lds[64][65];
  int blk = blockIdx.x, t = threadIdx.x;
  if (blk < 512) {
    int base = (blk * 256 + t) * 4;
    int s = base >> 8, i0 = base & 255;
    float ps = (float)s * (1.0f / 512.0f);
    float fs = (float)s;
    float2 o[4];
    for (int u = 0; u < 4; ++u) {
      int i = i0 + u;
      float sv = (2.0f * (float)i + 204.8f) * (1.0f / 716.8f);
      float scale = exp2f(ps * __log2f(sv));
      float inv_freq = exp2f((float)i * (-13.287712379549449f / 256.0f));
      float theta = fs * inv_freq;
      o[u] = make_float2(__sinf(theta) * scale, __cosf(theta) * scale);
    }
    *(float4*)&tab[base]     = make_float4(o[0].x, o[0].y, o[1].x, o[1].y);
    *(float4*)&tab[base + 2] = make_float4(o[2].x, o[2].y, o[3].x, o[3].y);
  } else if (blk < 2560) {
    int base = ((blk - 512) * 256 + t) * 4;
    float4 v = *(const float4*)(X + base);
    ushort4 o;
    o.x = f2bf(v.x); o.y = f2bf(v.y); o.z = f2bf(v.z); o.w = f2bf(v.w);
    *(ushort4*)(Xb + base) = o;
  } else {
    int wb = blk - 2560;                 // 0..191
    int which = wb >> 6;
    const float* W = which == 0 ? Wq : which == 1 ? Wk : Wv;
    unsigned short* Wt = which == 0 ? Wtq : which == 1 ? Wtk : Wtv;
    int tile = wb & 63;
    int tk = tile & 7, tn = tile >> 3;
    int k0 = tk * 64, n0 = tn * 64;
    for (int j = 0; j < 16; ++j) {
      int e = t + 256 * j;
      int r = e >> 6, c = e & 63;
      lds[r][c] = W[(size_t)(k0 + r) * DMODEL + (n0 + c)];
    }
    __syncthreads();
    for (int j = 0; j < 16; ++j) {
      int e = t + 256 * j;
      int r = e >> 6, c = e & 63;
      Wt[(size_t)(n0 + r) * DMODEL + (k0 + c)] = f2bf(lds[c][r]);
    }
  }
}

// ---- QKV GEMM, 2-phase double-buffered staging ----
// z=0 -> qraw, z=1 -> kraw (row-major bf16, RAW: transform happens in k_attn);
// z=2 -> vt transposed [b,h,d,s]
#define BM 128
#define BN 128
#define BK 64
#define KSTEPS (DMODEL / BK)
__global__ __launch_bounds__(256) void k_gemm(
    const unsigned short* __restrict__ A,
    const unsigned short* __restrict__ Btq, const unsigned short* __restrict__ Btk,
    const unsigned short* __restrict__ Btv,
    unsigned short* __restrict__ outq, unsigned short* __restrict__ outk,
    unsigned short* __restrict__ outvt) {
  int z = blockIdx.z;
  const unsigned short* Bt = (z == 0) ? Btq : (z == 1) ? Btk : Btv;
  __shared__ unsigned short Alds[2][BM * BK];   // linear, chunk-swizzled, dbuf
  __shared__ unsigned short Blds[2][BN * BK];
  int m0 = blockIdx.y * BM, n0 = blockIdx.x * BN;
  int t = threadIdx.x, lane = t & 63, w = t >> 6;
  int wr = w >> 1, wc = w & 1;
  f32x4 acc[4][4] = {};

  // stage K-step 0 into buf 0
  for (int j = 0; j < 4; ++j) {
    int chunk = w * 256 + j * 64 + lane;
    int r = chunk >> 3, cl = chunk & 7, cg = cl ^ (r & 7);
    gload16(&A[(size_t)(m0 + r) * DMODEL + cg * 8], &Alds[0][(w * 256 + j * 64) * 8]);
    gload16(&Bt[(size_t)(n0 + r) * DMODEL + cg * 8], &Blds[0][(w * 256 + j * 64) * 8]);
  }
  __syncthreads();
  int cur = 0;
  for (int ks = 0; ks < KSTEPS; ++ks) {
    if (ks + 1 < KSTEPS) {                       // prefetch next K-step into alt buf
      int k0 = (ks + 1) * BK;
      for (int j = 0; j < 4; ++j) {
        int chunk = w * 256 + j * 64 + lane;
        int r = chunk >> 3, cl = chunk & 7, cg = cl ^ (r & 7);
        gload16(&A[(size_t)(m0 + r) * DMODEL + k0 + cg * 8],
                &Alds[cur ^ 1][(w * 256 + j * 64) * 8]);
        gload16(&Bt[(size_t)(n0 + r) * DMODEL + k0 + cg * 8],
                &Blds[cur ^ 1][(w * 256 + j * 64) * 8]);
      }
    }
    for (int kk = 0; kk < 2; ++kk) {
      int ch = kk * 4 + (lane >> 4);
      short8 af[4], bfr[4];
      for (int mf = 0; mf < 4; ++mf) {
        int row = wr * 64 + mf * 16 + (lane & 15);
        af[mf] = *(const short8*)&Alds[cur][row * 64 + ((ch ^ (row & 7)) * 8)];
      }
      for (int nf = 0; nf < 4; ++nf) {
        int row = wc * 64 + nf * 16 + (lane & 15);
        bfr[nf] = *(const short8*)&Blds[cur][row * 64 + ((ch ^ (row & 7)) * 8)];
      }
      for (int mf = 0; mf < 4; ++mf)
        for (int nf = 0; nf < 4; ++nf)
          acc[mf][nf] = __builtin_amdgcn_mfma_f32_16x16x32_bf16(af[mf], bfr[nf], acc[mf][nf], 0, 0, 0);
    }
    __syncthreads();   // drains prefetch vmcnt + all waves done reading buf[cur]
    cur ^= 1;
  }
  if (z < 2) {
    unsigned short* out = (z == 0) ? outq : outk;
    for (int mf = 0; mf < 4; ++mf)
      for (int nf = 0; nf < 4; ++nf)
        for (int j = 0; j < 4; ++j) {
          int m = m0 + wr * 64 + mf * 16 + (lane >> 4) * 4 + j;
          int n = n0 + wc * 64 + nf * 16 + (lane & 15);
          out[(size_t)m * DMODEL + n] = f2bf(acc[mf][nf][j]);
        }
  } else {
    for (int mf = 0; mf < 4; ++mf)
      for (int nf = 0; nf < 4; ++nf) {
        int m = m0 + wr * 64 + mf * 16 + (lane >> 4) * 4;  // 4 consecutive s
        int n = n0 + wc * 64 + nf * 16 + (lane & 15);
        int b = m >> 11, s = m & (SEQ - 1);
        int h = n >> 6, d = n & 63;
        ushort4 pk;
        pk.x = f2bf(acc[mf][nf][0]); pk.y = f2bf(acc[mf][nf][1]);
        pk.z = f2bf(acc[mf][nf][2]); pk.w = f2bf(acc[mf][nf][3]);
        *(ushort4*)&outvt[((size_t)((b * NH + h) * HDIM + d)) * SEQ + s] = pk;
      }
  }
}

// ---- banded MSR attention with FUSED xpos/silu/groupnorm + residual + relu ----
// stage raw q slice + NT raw k tiles + NT v tiles; barrier; 256 threads each
// transform one complete (row, 64-ch head slice) in registers (thread-local GN,
// zero shuffles); write back; barrier; MFMA compute (P per-wave-private).
__global__ __launch_bounds__(256) void k_attn(
    const unsigned short* __restrict__ q, const unsigned short* __restrict__ k,
    const unsigned short* __restrict__ vt, const float* __restrict__ X,
    const float2* __restrict__ tab,
    const float* __restrict__ gnw, const float* __restrict__ gnb,
    float* __restrict__ out) {
  __shared__ unsigned short qlds[64 * 64];       // raw->transformed q slice
  __shared__ unsigned short klds[NT][64 * 64];   // raw->transformed k tiles
  __shared__ unsigned short vlds[NT][64 * 64];   // [d][key]
  __shared__ unsigned short plds[4][16][72];     // per-wave [qrow][key]
  int qt = blockIdx.x;
  int bh = blockIdx.y;
  int b = bh >> 3, h = bh & 7;
  int t = threadIdx.x, lane = t & 63, w = t >> 6;
  int n0 = qt * 64;
  int nw = n0 + w * 16;
  int g = lane >> 4;
  const float log2g = -0.15200309344504997f;   // log2(0.9)
  int kt_lo = qt - (NT - 1); if (kt_lo < 0) kt_lo = 0;
  int ntiles = qt - kt_lo + 1;

  // ---- stage raw q, k, v ----
  for (int j = 0; j < 2; ++j) {
    int chunk = w * 128 + j * 64 + lane;          // 0..511
    int r = chunk >> 3, cl = chunk & 7, cg = cl ^ (r & 7);
    gload16(&q[((size_t)(b * SEQ + n0 + r)) * DMODEL + h * HDIM + cg * 8],
            &qlds[(w * 128 + j * 64) * 8]);
  }
  for (int tt = 0; tt < ntiles; ++tt) {
    int m0 = (kt_lo + tt) * 64;
    for (int j = 0; j < 2; ++j) {
      int chunk = w * 128 + j * 64 + lane;
      int r = chunk >> 3, cl = chunk & 7, cg = cl ^ (r & 7);
      gload16(&k[((size_t)(b * SEQ + m0 + r)) * DMODEL + h * HDIM + cg * 8],
              &klds[tt][(w * 128 + j * 64) * 8]);
      gload16(&vt[((size_t)((b * NH + h) * HDIM + r)) * SEQ + m0 + cg * 8],
              &vlds[tt][(w * 128 + j * 64) * 8]);
    }
  }
  __syncthreads();   // staging complete

  // ---- transform: thread -> one (row, head-slice); t<64: q row, else k row ----
  int nrows = 64 + ntiles * 64;
  if (t < nrows) {
    bool isq = (t < 64);
    int kr = t - 64;
    int tt = kr >> 6, rr = isq ? t : (kr & 63);
    unsigned short* base = isq ? qlds : &klds[tt][0];
    int s_abs = isq ? (n0 + rr) : ((kt_lo + tt) * 64 + rr);
    float x[64];
    #pragma unroll
    for (int c = 0; c < 8; ++c) {
      ushort8_t u = *(const ushort8_t*)&base[(rr * 8 + (c ^ (rr & 7))) * 8];
      #pragma unroll
      for (int e = 0; e < 8; ++e) x[c * 8 + e] = bf2f(u[e]);
    }
    const float4* tb = (const float4*)&tab[(size_t)s_abs * HALF + h * 32];
    #pragma unroll
    for (int p2 = 0; p2 < 16; ++p2) {
      float4 tc = tb[p2];                         // (sn0,cs0,sn1,cs1)
      float x1 = x[4 * p2], x2 = x[4 * p2 + 1];
      x[4 * p2]     = x1 * tc.y - x2 * tc.x;
      x[4 * p2 + 1] = x2 * tc.y + x1 * tc.x;
      x1 = x[4 * p2 + 2]; x2 = x[4 * p2 + 3];
      x[4 * p2 + 2] = x1 * tc.w - x2 * tc.z;
      x[4 * p2 + 3] = x2 * tc.w + x1 * tc.z;
    }
    if (isq) {
      #pragma unroll
      for (int c = 0; c < 64; ++c) x[c] = x[c] / (1.0f + __expf(-x[c]));
    } else {
      float s1 = 0.0f, s2 = 0.0f;
      #pragma unroll
      for (int c = 0; c < 64; ++c) { s1 += x[c]; s2 += x[c] * x[c]; }
      float mu = s1 * (1.0f / 64.0f);
      float var = s2 * (1.0f / 64.0f) - mu * mu;
      float rstd = rsqrtf(var + 1e-5f);
      const float4* gw = (const float4*)&gnw[h * HDIM];
      const float4* gb = (const float4*)&gnb[h * HDIM];
      #pragma unroll
      for (int c4 = 0; c4 < 16; ++c4) {
        float4 wv = gw[c4], bv = gb[c4];
        x[c4 * 4 + 0] = (x[c4 * 4 + 0] - mu) * rstd * wv.x + bv.x;
        x[c4 * 4 + 1] = (x[c4 * 4 + 1] - mu) * rstd * wv.y + bv.y;
        x[c4 * 4 + 2] = (x[c4 * 4 + 2] - mu) * rstd * wv.z + bv.z;
        x[c4 * 4 + 3] = (x[c4 * 4 + 3] - mu) * rstd * wv.w + bv.w;
      }
    }
    #pragma unroll
    for (int c = 0; c < 8; ++c) {
      ushort8_t o;
      #pragma unroll
      for (int e = 0; e < 8; ++e) o[e] = f2bf(x[c * 8 + e]);
      *(ushort8_t*)&base[(rr * 8 + (c ^ (rr & 7))) * 8] = o;
    }
  }
  __syncthreads();   // transforms visible

  // ---- compute ----
  short8 aq[2];
  {
    int qrow = w * 16 + (lane & 15);
    for (int kk = 0; kk < 2; ++kk) {
      int slot = (kk * 4 + g) ^ (qrow & 7);
      aq[kk] = *(const short8*)&qlds[(qrow * 8 + slot) * 8];
    }
  }
  float sk[4];   // gamma^{-(col in tile)}
  for (int nf = 0; nf < 4; ++nf)
    sk[nf] = exp2f(-(float)(nf * 16 + (lane & 15)) * log2g);
  int nrb = nw + g * 4;
  f32x4 o[4] = {};
  for (int tt = 0; tt < ntiles; ++tt) {
    int m0 = (kt_lo + tt) * 64;
    float sq_[4];
    for (int j = 0; j < 4; ++j)
      sq_[j] = exp2f((float)(nrb + j - m0) * log2g);   // gamma^{q - m0}
    f32x4 sc[4] = {};
    for (int kk = 0; kk < 2; ++kk) {
      int ch = kk * 4 + g;
      for (int nf = 0; nf < 4; ++nf) {
        int row = nf * 16 + (lane & 15);
        short8 bk = *(const short8*)&klds[tt][row * 64 + ((ch ^ (row & 7)) * 8)];
        sc[nf] = __builtin_amdgcn_mfma_f32_16x16x32_bf16(aq[kk], bk, sc[nf], 0, 0, 0);
      }
    }
    for (int nf = 0; nf < 4; ++nf) {
      int cin = nf * 16 + (lane & 15);
      for (int j = 0; j < 4; ++j) {
        int dlt = nrb + j - (m0 + cin);
        float f = (dlt >= 0) ? sq_[j] * sk[nf] : 0.0f;
        plds[w][g * 4 + j][cin] = f2bf(sc[nf][j] * f);
      }
    }
    // no barrier: each wave reads only its own plds[w] region
    for (int kk = 0; kk < 2; ++kk) {
      int ch = kk * 4 + g;
      short8 pa = *(const short8*)&plds[w][lane & 15][kk * 32 + g * 8];
      for (int nf = 0; nf < 4; ++nf) {
        int row = nf * 16 + (lane & 15);
        short8 bv = *(const short8*)&vlds[tt][row * 64 + ((ch ^ (row & 7)) * 8)];
        o[nf] = __builtin_amdgcn_mfma_f32_16x16x32_bf16(pa, bv, o[nf], 0, 0, 0);
      }
    }
  }
  for (int nf = 0; nf < 4; ++nf)
    for (int j = 0; j < 4; ++j) {
      int srow = nw + g * 4 + j;
      int col = h * HDIM + nf * 16 + (lane & 15);
      size_t off = ((size_t)(b * SEQ + srow)) * DMODEL + col;
      float val = o[nf][j] + X[off];
      out[off] = val > 0.0f ? val : 0.0f;
    }
}

extern "C" void kernel_launch(void* const* d_in, const int* in_sizes, int n_in,
                              void* d_out, int out_size, void* d_ws, size_t ws_size,
                              hipStream_t stream) {
  const float* X   = (const float*)d_in[0];
  const float* Wq  = (const float*)d_in[1];
  const float* Wk  = (const float*)d_in[2];
  const float* Wv  = (const float*)d_in[3];
  const float* gnw = (const float*)d_in[4];
  const float* gnb = (const float*)d_in[5];
  float* out = (float*)d_out;
  char* ws = (char*)d_ws;

  float2*         tab  = (float2*)ws;                                   // 4 MB
  unsigned short* Xb   = (unsigned short*)(ws + (4u << 20));            // 4 MB
  unsigned short* Wtq  = (unsigned short*)(ws + (8u << 20));            // 0.5 MB each
  unsigned short* Wtk  = Wtq + 512 * 512;
  unsigned short* Wtv  = Wtk + 512 * 512;
  unsigned short* qb   = (unsigned short*)(ws + (8u << 20) + 3u * 512 * 512 * 2);
  unsigned short* kb   = qb + (size_t)NROWS * DMODEL;
  unsigned short* vt   = kb + (size_t)NROWS * DMODEL;

  k_prep<<<dim3(2752), dim3(256), 0, stream>>>(X, Wq, Wk, Wv, tab, Xb, Wtq, Wtk, Wtv);
  k_gemm<<<dim3(4, 32, 3), dim3(256), 0, stream>>>(Xb, Wtq, Wtk, Wtv, qb, kb, vt);
  k_attn<<<dim3(32, 16), dim3(256), 0, stream>>>(qb, kb, vt, X, tab, gnw, gnb, out);
}

// Round 6
// 40.524 us; speedup vs baseline: 1.1787x; 1.1787x over previous
//
#include <hip/hip_runtime.h>
#include <hip/hip_bf16.h>
#include <math.h>

#define NB 2
#define SEQ 2048
#define DMODEL 512
#define NH 8
#define HDIM 64
#define NROWS (NB*SEQ)
#define HALF 256
#define NT 3   // key-tile lookback (min omitted delta = 129, gamma^129/(1-g)*|sv| ~ 6e-4)

typedef __attribute__((ext_vector_type(8))) short short8;
typedef __attribute__((ext_vector_type(4))) float f32x4;
typedef __attribute__((ext_vector_type(8))) unsigned short ushort8_t;

__device__ __forceinline__ unsigned short f2bf(float f) {
  union { float f; unsigned u; } v; v.f = f;
  unsigned r = v.u + 0x7fffu + ((v.u >> 16) & 1u);
  return (unsigned short)(r >> 16);
}
__device__ __forceinline__ float bf2f(unsigned short h) {
  union { unsigned u; float f; } v; v.u = ((unsigned)h) << 16;
  return v.f;
}

// async global->LDS, 16B per lane; LDS dest is wave-uniform base + lane*16
__device__ __forceinline__ void gload16(const void* g, void* l) {
  __builtin_amdgcn_global_load_lds(
      (const __attribute__((address_space(1))) unsigned int*)g,
      (__attribute__((address_space(3))) unsigned int*)l, 16, 0, 0);
}

// ---- fused prep: xpos tables | X->bf16 | W transpose+convert x3 ----
__global__ __launch_bounds__(256) void k_prep(
    const float* __restrict__ X, const float* __restrict__ Wq,
    const float* __restrict__ Wk, const float* __restrict__ Wv,
    float2* __restrict__ tab, unsigned short* __restrict__ Xb,
    unsigned short* __restrict__ Wtq, unsigned short* __restrict__ Wtk,
    unsigned short* __restrict__ Wtv) {
  __shared__ float lds[64][65];
  int blk = blockIdx.x, t = threadIdx.x;
  if (blk < 512) {
    int base = (blk * 256 + t) * 4;
    int s = base >> 8, i0 = base & 255;
    float ps = (float)s * (1.0f / 512.0f);
    float fs = (float)s;
    float2 o[4];
    for (int u = 0; u < 4; ++u) {
      int i = i0 + u;
      float sv = (2.0f * (float)i + 204.8f) * (1.0f / 716.8f);
      float scale = exp2f(ps * __log2f(sv));
      float inv_freq = exp2f((float)i * (-13.287712379549449f / 256.0f));
      float theta = fs * inv_freq;
      o[u] = make_float2(__sinf(theta) * scale, __cosf(theta) * scale);
    }
    *(float4*)&tab[base]     = make_float4(o[0].x, o[0].y, o[1].x, o[1].y);
    *(float4*)&tab[base + 2] = make_float4(o[2].x, o[2].y, o[3].x, o[3].y);
  } else if (blk < 2560) {
    int base = ((blk - 512) * 256 + t) * 4;
    float4 v = *(const float4*)(X + base);
    ushort4 o;
    o.x = f2bf(v.x); o.y = f2bf(v.y); o.z = f2bf(v.z); o.w = f2bf(v.w);
    *(ushort4*)(Xb + base) = o;
  } else {
    int wb = blk - 2560;                 // 0..191
    int which = wb >> 6;
    const float* W = which == 0 ? Wq : which == 1 ? Wk : Wv;
    unsigned short* Wt = which == 0 ? Wtq : which == 1 ? Wtk : Wtv;
    int tile = wb & 63;
    int tk = tile & 7, tn = tile >> 3;
    int k0 = tk * 64, n0 = tn * 64;
    for (int j = 0; j < 16; ++j) {
      int e = t + 256 * j;
      int r = e >> 6, c = e & 63;
      lds[r][c] = W[(size_t)(k0 + r) * DMODEL + (n0 + c)];
    }
    __syncthreads();
    for (int j = 0; j < 16; ++j) {
      int e = t + 256 * j;
      int r = e >> 6, c = e & 63;
      Wt[(size_t)(n0 + r) * DMODEL + (k0 + c)] = f2bf(lds[c][r]);
    }
  }
}

// ---- QKV GEMM, 2-phase double-buffered staging ----
// z=0 -> qraw, z=1 -> kraw (row-major bf16); z=2 -> vt transposed [b,h,d,s]
#define BM 128
#define BN 128
#define BK 64
#define KSTEPS (DMODEL / BK)
__global__ __launch_bounds__(256) void k_gemm(
    const unsigned short* __restrict__ A,
    const unsigned short* __restrict__ Btq, const unsigned short* __restrict__ Btk,
    const unsigned short* __restrict__ Btv,
    unsigned short* __restrict__ outq, unsigned short* __restrict__ outk,
    unsigned short* __restrict__ outvt) {
  int z = blockIdx.z;
  const unsigned short* Bt = (z == 0) ? Btq : (z == 1) ? Btk : Btv;
  __shared__ unsigned short Alds[2][BM * BK];   // linear, chunk-swizzled, dbuf
  __shared__ unsigned short Blds[2][BN * BK];
  int m0 = blockIdx.y * BM, n0 = blockIdx.x * BN;
  int t = threadIdx.x, lane = t & 63, w = t >> 6;
  int wr = w >> 1, wc = w & 1;
  f32x4 acc[4][4] = {};

  for (int j = 0; j < 4; ++j) {
    int chunk = w * 256 + j * 64 + lane;
    int r = chunk >> 3, cl = chunk & 7, cg = cl ^ (r & 7);
    gload16(&A[(size_t)(m0 + r) * DMODEL + cg * 8], &Alds[0][(w * 256 + j * 64) * 8]);
    gload16(&Bt[(size_t)(n0 + r) * DMODEL + cg * 8], &Blds[0][(w * 256 + j * 64) * 8]);
  }
  __syncthreads();
  int cur = 0;
  for (int ks = 0; ks < KSTEPS; ++ks) {
    if (ks + 1 < KSTEPS) {                       // prefetch next K-step into alt buf
      int k0 = (ks + 1) * BK;
      for (int j = 0; j < 4; ++j) {
        int chunk = w * 256 + j * 64 + lane;
        int r = chunk >> 3, cl = chunk & 7, cg = cl ^ (r & 7);
        gload16(&A[(size_t)(m0 + r) * DMODEL + k0 + cg * 8],
                &Alds[cur ^ 1][(w * 256 + j * 64) * 8]);
        gload16(&Bt[(size_t)(n0 + r) * DMODEL + k0 + cg * 8],
                &Blds[cur ^ 1][(w * 256 + j * 64) * 8]);
      }
    }
    for (int kk = 0; kk < 2; ++kk) {
      int ch = kk * 4 + (lane >> 4);
      short8 af[4], bfr[4];
      for (int mf = 0; mf < 4; ++mf) {
        int row = wr * 64 + mf * 16 + (lane & 15);
        af[mf] = *(const short8*)&Alds[cur][row * 64 + ((ch ^ (row & 7)) * 8)];
      }
      for (int nf = 0; nf < 4; ++nf) {
        int row = wc * 64 + nf * 16 + (lane & 15);
        bfr[nf] = *(const short8*)&Blds[cur][row * 64 + ((ch ^ (row & 7)) * 8)];
      }
      for (int mf = 0; mf < 4; ++mf)
        for (int nf = 0; nf < 4; ++nf)
          acc[mf][nf] = __builtin_amdgcn_mfma_f32_16x16x32_bf16(af[mf], bfr[nf], acc[mf][nf], 0, 0, 0);
    }
    __syncthreads();   // drains prefetch vmcnt + all waves done reading buf[cur]
    cur ^= 1;
  }
  if (z < 2) {
    unsigned short* out = (z == 0) ? outq : outk;
    for (int mf = 0; mf < 4; ++mf)
      for (int nf = 0; nf < 4; ++nf)
        for (int j = 0; j < 4; ++j) {
          int m = m0 + wr * 64 + mf * 16 + (lane >> 4) * 4 + j;
          int n = n0 + wc * 64 + nf * 16 + (lane & 15);
          out[(size_t)m * DMODEL + n] = f2bf(acc[mf][nf][j]);
        }
  } else {
    for (int mf = 0; mf < 4; ++mf)
      for (int nf = 0; nf < 4; ++nf) {
        int m = m0 + wr * 64 + mf * 16 + (lane >> 4) * 4;  // 4 consecutive s
        int n = n0 + wc * 64 + nf * 16 + (lane & 15);
        int b = m >> 11, s = m & (SEQ - 1);
        int h = n >> 6, d = n & 63;
        ushort4 pk;
        pk.x = f2bf(acc[mf][nf][0]); pk.y = f2bf(acc[mf][nf][1]);
        pk.z = f2bf(acc[mf][nf][2]); pk.w = f2bf(acc[mf][nf][3]);
        *(ushort4*)&outvt[((size_t)((b * NH + h) * HDIM + d)) * SEQ + s] = pk;
      }
  }
}

// ---- fused xpos (+silu for q | +groupnorm for k), in place, 1 wave = 1 row ----
__global__ __launch_bounds__(256) void k_qk_transform(
    unsigned short* __restrict__ qb, unsigned short* __restrict__ kb,
    const float2* __restrict__ tab,
    const float* __restrict__ gnw, const float* __restrict__ gnb) {
  int lane = threadIdx.x & 63;
  int w = threadIdx.x >> 6;
  int row = blockIdx.x * 4 + w;                  // 0..4095
  int isk = blockIdx.y;
  unsigned short* buf = isk ? kb : qb;
  int s = row & (SEQ - 1);
  size_t off = (size_t)row * DMODEL + lane * 8;
  ushort8_t raw = *(const ushort8_t*)&buf[off];
  float v[8], r[8];
  for (int j = 0; j < 8; ++j) v[j] = bf2f(raw[j]);
  float4 t0 = *(const float4*)&tab[s * HALF + lane * 4];
  float4 t1 = *(const float4*)&tab[s * HALF + lane * 4 + 2];
  float sn[4] = {t0.x, t0.z, t1.x, t1.z};
  float cs[4] = {t0.y, t0.w, t1.y, t1.w};
  for (int p = 0; p < 4; ++p) {
    float x1 = v[2 * p], x2 = v[2 * p + 1];
    r[2 * p]     = x1 * cs[p] - x2 * sn[p];
    r[2 * p + 1] = x2 * cs[p] + x1 * sn[p];
  }
  if (!isk) {
    for (int j = 0; j < 8; ++j) r[j] = r[j] / (1.0f + __expf(-r[j]));
  } else {
    float sum = 0.0f, sq = 0.0f;
    for (int j = 0; j < 8; ++j) { sum += r[j]; sq += r[j] * r[j]; }
    for (int m = 1; m < 8; m <<= 1) { sum += __shfl_xor(sum, m); sq += __shfl_xor(sq, m); }
    float mu = sum * (1.0f / 64.0f);
    float var = sq * (1.0f / 64.0f) - mu * mu;
    float rstd = rsqrtf(var + 1e-5f);
    float4 w0 = *(const float4*)&gnw[lane * 8];
    float4 w1 = *(const float4*)&gnw[lane * 8 + 4];
    float4 b0 = *(const float4*)&gnb[lane * 8];
    float4 b1 = *(const float4*)&gnb[lane * 8 + 4];
    float wv[8] = {w0.x, w0.y, w0.z, w0.w, w1.x, w1.y, w1.z, w1.w};
    float bv[8] = {b0.x, b0.y, b0.z, b0.w, b1.x, b1.y, b1.z, b1.w};
    for (int j = 0; j < 8; ++j) r[j] = (r[j] - mu) * rstd * wv[j] + bv[j];
  }
  ushort8_t o;
  for (int j = 0; j < 8; ++j) o[j] = f2bf(r[j]);
  *(ushort8_t*)&buf[off] = o;
}

// ---- banded MSR attention, fused residual + relu ----
// stage ALL NT tiles up front, ONE barrier; X residual prefetched to regs early
__global__ __launch_bounds__(256) void k_attn(
    const unsigned short* __restrict__ q, const unsigned short* __restrict__ k,
    const unsigned short* __restrict__ vt, const float* __restrict__ X,
    float* __restrict__ out) {
  __shared__ unsigned short klds[NT][64 * 64];   // linear, chunk-swizzled
  __shared__ unsigned short vlds[NT][64 * 64];   // [d][key]
  __shared__ unsigned short plds[4][16][72];     // per-wave [qrow][key]
  int qt = blockIdx.x;
  int bh = blockIdx.y;
  int b = bh >> 3, h = bh & 7;
  int t = threadIdx.x, lane = t & 63, w = t >> 6;
  int n0 = qt * 64;
  int nw = n0 + w * 16;
  int g = lane >> 4;
  const float log2g = -0.15200309344504997f;   // log2(0.9)
  short8 aq[2];
  for (int kk = 0; kk < 2; ++kk) {
    size_t off = ((size_t)(b * SEQ + nw + (lane & 15))) * DMODEL + h * HDIM + kk * 32 + g * 8;
    aq[kk] = *(const short8*)&q[off];
  }
  int kt_lo = qt - (NT - 1); if (kt_lo < 0) kt_lo = 0;
  int ntiles = qt - kt_lo + 1;
  for (int tt = 0; tt < ntiles; ++tt) {
    int m0 = (kt_lo + tt) * 64;
    for (int j = 0; j < 2; ++j) {
      int chunk = w * 128 + j * 64 + lane;        // 0..511
      int r = chunk >> 3, cl = chunk & 7, cg = cl ^ (r & 7);
      gload16(&k[((size_t)(b * SEQ + m0 + r)) * DMODEL + h * HDIM + cg * 8],
              &klds[tt][(w * 128 + j * 64) * 8]);
      gload16(&vt[((size_t)((b * NH + h) * HDIM + r)) * SEQ + m0 + cg * 8],
              &vlds[tt][(w * 128 + j * 64) * 8]);
    }
  }
  // prefetch residual X into regs (hides HBM latency under staging + compute)
  float xr[4][4];
  for (int nf = 0; nf < 4; ++nf)
    for (int j = 0; j < 4; ++j) {
      int srow = nw + g * 4 + j;
      int col = h * HDIM + nf * 16 + (lane & 15);
      xr[nf][j] = X[((size_t)(b * SEQ + srow)) * DMODEL + col];
    }
  float sk[4];   // gamma^{-(col in tile)}
  for (int nf = 0; nf < 4; ++nf)
    sk[nf] = exp2f(-(float)(nf * 16 + (lane & 15)) * log2g);
  int nrb = nw + g * 4;
  f32x4 o[4] = {};
  __syncthreads();   // drains all staging loads
  for (int tt = 0; tt < ntiles; ++tt) {
    int m0 = (kt_lo + tt) * 64;
    float sq_[4];
    for (int j = 0; j < 4; ++j)
      sq_[j] = exp2f((float)(nrb + j - m0) * log2g);   // gamma^{q - m0}
    f32x4 sc[4] = {};
    for (int kk = 0; kk < 2; ++kk) {
      int ch = kk * 4 + g;
      for (int nf = 0; nf < 4; ++nf) {
        int row = nf * 16 + (lane & 15);
        short8 bk = *(const short8*)&klds[tt][row * 64 + ((ch ^ (row & 7)) * 8)];
        sc[nf] = __builtin_amdgcn_mfma_f32_16x16x32_bf16(aq[kk], bk, sc[nf], 0, 0, 0);
      }
    }
    for (int nf = 0; nf < 4; ++nf) {
      int cin = nf * 16 + (lane & 15);
      for (int j = 0; j < 4; ++j) {
        int dlt = nrb + j - (m0 + cin);
        float f = (dlt >= 0) ? sq_[j] * sk[nf] : 0.0f;
        plds[w][g * 4 + j][cin] = f2bf(sc[nf][j] * f);
      }
    }
    // no barrier: each wave reads only its own plds[w] region
    for (int kk = 0; kk < 2; ++kk) {
      int ch = kk * 4 + g;
      short8 pa = *(const short8*)&plds[w][lane & 15][kk * 32 + g * 8];
      for (int nf = 0; nf < 4; ++nf) {
        int row = nf * 16 + (lane & 15);
        short8 bv = *(const short8*)&vlds[tt][row * 64 + ((ch ^ (row & 7)) * 8)];
        o[nf] = __builtin_amdgcn_mfma_f32_16x16x32_bf16(pa, bv, o[nf], 0, 0, 0);
      }
    }
  }
  for (int nf = 0; nf < 4; ++nf)
    for (int j = 0; j < 4; ++j) {
      int srow = nw + g * 4 + j;
      int col = h * HDIM + nf * 16 + (lane & 15);
      size_t off = ((size_t)(b * SEQ + srow)) * DMODEL + col;
      float val = o[nf][j] + xr[nf][j];
      out[off] = val > 0.0f ? val : 0.0f;
    }
}

extern "C" void kernel_launch(void* const* d_in, const int* in_sizes, int n_in,
                              void* d_out, int out_size, void* d_ws, size_t ws_size,
                              hipStream_t stream) {
  const float* X   = (const float*)d_in[0];
  const float* Wq  = (const float*)d_in[1];
  const float* Wk  = (const float*)d_in[2];
  const float* Wv  = (const float*)d_in[3];
  const float* gnw = (const float*)d_in[4];
  const float* gnb = (const float*)d_in[5];
  float* out = (float*)d_out;
  char* ws = (char*)d_ws;

  float2*         tab  = (float2*)ws;                                   // 4 MB
  unsigned short* Xb   = (unsigned short*)(ws + (4u << 20));            // 4 MB
  unsigned short* Wtq  = (unsigned short*)(ws + (8u << 20));            // 0.5 MB each
  unsigned short* Wtk  = Wtq + 512 * 512;
  unsigned short* Wtv  = Wtk + 512 * 512;
  unsigned short* qb   = (unsigned short*)(ws + (8u << 20) + 3u * 512 * 512 * 2);
  unsigned short* kb   = qb + (size_t)NROWS * DMODEL;
  unsigned short* vt   = kb + (size_t)NROWS * DMODEL;

  k_prep<<<dim3(2752), dim3(256), 0, stream>>>(X, Wq, Wk, Wv, tab, Xb, Wtq, Wtk, Wtv);
  k_gemm<<<dim3(4, 32, 3), dim3(256), 0, stream>>>(Xb, Wtq, Wtk, Wtv, qb, kb, vt);
  k_qk_transform<<<dim3(1024, 2), dim3(256), 0, stream>>>(qb, kb, tab, gnw, gnb);
  k_attn<<<dim3(32, 16), dim3(256), 0, stream>>>(qb, kb, vt, X, out);
}